// Round 1
// baseline (112.520 us; speedup 1.0000x reference)
//
#include <hip/hip_runtime.h>

#define N_ROWS 16384
#define L_DIM  4096

// ---------------- Kernel A: tiled transpose W (L x L, f32) -> Wt ----------------
// 64x64 tile, 256 threads, float4 on both global load and store.
__global__ __launch_bounds__(256) void transpose_k(const float* __restrict__ in,
                                                   float* __restrict__ out) {
    __shared__ float tile[64][65];  // +1 pad: conflict-free transposed reads
    const int x0 = blockIdx.x * 64;   // input col tile
    const int y0 = blockIdx.y * 64;   // input row tile
    const int tid = threadIdx.x;
    const int lx = (tid & 15) * 4;    // col within tile (float4)
    const int ly = tid >> 4;          // row within tile (0..15), step 16

    // load: smem[ry][cx] = in[y0+ry][x0+cx]  (coalesced)
    #pragma unroll
    for (int r = 0; r < 64; r += 16) {
        const float4 v = *(const float4*)&in[(size_t)(y0 + ly + r) * L_DIM + (x0 + lx)];
        tile[ly + r][lx + 0] = v.x;
        tile[ly + r][lx + 1] = v.y;
        tile[ly + r][lx + 2] = v.z;
        tile[ly + r][lx + 3] = v.w;
    }
    __syncthreads();

    // store: out[x0+rx][y0+cy] = tile[cy][rx]  (coalesced)
    #pragma unroll
    for (int r = 0; r < 64; r += 16) {
        const int rx = ly + r;
        float4 v;
        v.x = tile[lx + 0][rx];
        v.y = tile[lx + 1][rx];
        v.z = tile[lx + 2][rx];
        v.w = tile[lx + 3][rx];
        *(float4*)&out[(size_t)(x0 + rx) * L_DIM + (y0 + lx)] = v;
    }
}

// ---------------- Kernel B: out[i,:] = zw[i] * Wt[w[i],:] + b[:] ----------------
__global__ __launch_bounds__(256) void pnet_main(const int* __restrict__ w,
                                                 const float* __restrict__ z,
                                                 const float* __restrict__ Wt,
                                                 const float* __restrict__ b,
                                                 float* __restrict__ out) {
    const int i  = blockIdx.x;
    const int wi = w[i];                              // block-uniform
    const float zw = z[(size_t)i * L_DIM + wi];       // block-uniform

    const float4* __restrict__ Wrow = (const float4*)&Wt[(size_t)wi * L_DIM];
    const float4* __restrict__ bv   = (const float4*)b;
    float4* __restrict__ orow       = (float4*)&out[(size_t)i * L_DIM];

    #pragma unroll
    for (int v = threadIdx.x; v < L_DIM / 4; v += 256) {
        const float4 wv = Wrow[v];
        const float4 bb = bv[v];
        float4 o;
        o.x = fmaf(zw, wv.x, bb.x);
        o.y = fmaf(zw, wv.y, bb.y);
        o.z = fmaf(zw, wv.z, bb.z);
        o.w = fmaf(zw, wv.w, bb.w);
        orow[v] = o;
    }
}

// ---------------- Fallback (ws too small): strided column reads of W ----------------
__global__ __launch_bounds__(256) void pnet_direct(const int* __restrict__ w,
                                                   const float* __restrict__ z,
                                                   const float* __restrict__ W,
                                                   const float* __restrict__ b,
                                                   float* __restrict__ out) {
    const int i  = blockIdx.x;
    const int wi = w[i];
    const float zw = z[(size_t)i * L_DIM + wi];
    for (int j = threadIdx.x; j < L_DIM; j += 256) {
        out[(size_t)i * L_DIM + j] = fmaf(zw, W[(size_t)j * L_DIM + wi], b[j]);
    }
}

extern "C" void kernel_launch(void* const* d_in, const int* in_sizes, int n_in,
                              void* d_out, int out_size, void* d_ws, size_t ws_size,
                              hipStream_t stream) {
    const int*   w = (const int*)d_in[0];
    const float* z = (const float*)d_in[1];
    const float* W = (const float*)d_in[2];
    const float* b = (const float*)d_in[3];
    float* out = (float*)d_out;

    const size_t wt_bytes = (size_t)L_DIM * L_DIM * sizeof(float);

    if (ws_size >= wt_bytes) {
        float* Wt = (float*)d_ws;
        dim3 tgrid(L_DIM / 64, L_DIM / 64);
        transpose_k<<<tgrid, 256, 0, stream>>>(W, Wt);
        pnet_main<<<N_ROWS, 256, 0, stream>>>(w, z, Wt, b, out);
    } else {
        pnet_direct<<<N_ROWS, 256, 0, stream>>>(w, z, W, b, out);
    }
}

// Round 2
// 74.846 us; speedup vs baseline: 1.5034x; 1.5034x over previous
//
#include <hip/hip_runtime.h>

#define N_ROWS 16384
#define L_DIM  4096
#define CG     16                 // W columns (locations) per block
#define JT     1024               // output-j columns per block
#define PASS   1024               // i's scanned per pass (== list capacity, no overflow)
#define NPASS  (N_ROWS / PASS)    // 16
#define PITCH  (JT + 4)           // LDS row pitch (pad keeps 16B align + kills conflicts)

// out[i, j] = z[i, w[i]] * W[j, w[i]] + b[j]
// Block (g, t): locations l0 = g*CG .. +CG, j-range j0 = t*JT .. +JT.
// Stage W[j0:j0+JT, l0:l0+CG] transposed in LDS (read exactly once from HBM),
// scan w[] for rows with w[i] in this location group, stream their output rows.
__global__ __launch_bounds__(256, 2) void pnet_fused(
    const int* __restrict__ w,
    const float* __restrict__ z,
    const float* __restrict__ W,
    const float* __restrict__ b,
    float* __restrict__ out)
{
    __shared__ float tile[CG * PITCH];   // tile[c*PITCH + r] = W[j0+r][l0+c]
    __shared__ int   list[PASS];         // packed (c<<16)|i
    __shared__ float zlist[PASS];
    __shared__ int   cnt[NPASS];

    const int tid = threadIdx.x;
    const int l0  = blockIdx.x * CG;
    const int j0  = blockIdx.y * JT;

    if (tid < NPASS) cnt[tid] = 0;

    // ---- stage: coalesced float4 reads, transposed scalar LDS writes (2-way, free) ----
    {
        const int q     = tid & 3;        // which 4-col chunk
        const int rbase = tid >> 2;       // row within tile, step 64
        #pragma unroll
        for (int it = 0; it < JT / 64; ++it) {
            const int r = rbase + it * 64;
            const float4 v = *(const float4*)&W[(size_t)(j0 + r) * L_DIM + l0 + 4 * q];
            tile[(4 * q + 0) * PITCH + r] = v.x;
            tile[(4 * q + 1) * PITCH + r] = v.y;
            tile[(4 * q + 2) * PITCH + r] = v.z;
            tile[(4 * q + 3) * PITCH + r] = v.w;
        }
    }

    // per-lane bias fragment: lane covers j = j0 + (k*64 + lane)*4 .. +3
    const int wid  = tid >> 6;
    const int lane = tid & 63;
    float4 bb[4];
    #pragma unroll
    for (int k = 0; k < 4; ++k)
        bb[k] = *(const float4*)&b[j0 + (k * 64 + lane) * 4];

    __syncthreads();

    for (int p = 0; p < NPASS; ++p) {
        // ---- scan this pass's i-range; append matches + gather zw ----
        {
            const int i0  = p * PASS + tid * 4;
            const int4 wv = *(const int4*)&w[i0];
            const int vals[4] = {wv.x, wv.y, wv.z, wv.w};
            #pragma unroll
            for (int e = 0; e < 4; ++e) {
                const unsigned c = (unsigned)(vals[e] - l0);
                if (c < CG) {
                    const int i   = i0 + e;
                    const int pos = atomicAdd(&cnt[p], 1);
                    list[pos]  = i | ((int)c << 16);
                    zlist[pos] = z[(size_t)i * L_DIM + vals[e]];
                }
            }
        }
        __syncthreads();

        // ---- each wave streams one matched row at a time ----
        const int n = cnt[p];
        for (int e = wid; e < n; e += 4) {
            const int   packed = list[e];
            const int   i      = packed & 0xFFFF;
            const int   c      = packed >> 16;
            const float zw     = zlist[e];
            const float* trow  = &tile[c * PITCH];
            float*       orow  = &out[(size_t)i * L_DIM + j0];
            #pragma unroll
            for (int k = 0; k < 4; ++k) {
                const int jj = (k * 64 + lane) * 4;
                const float4 wv4 = *(const float4*)&trow[jj];   // ds_read_b128, conflict-free
                float4 o;
                o.x = fmaf(zw, wv4.x, bb[k].x);
                o.y = fmaf(zw, wv4.y, bb[k].y);
                o.z = fmaf(zw, wv4.z, bb[k].z);
                o.w = fmaf(zw, wv4.w, bb[k].w);
                *(float4*)&orow[jj] = o;                        // coalesced 1KB/wave stores
            }
        }
        __syncthreads();  // protects list/zlist reuse next pass
    }
}

extern "C" void kernel_launch(void* const* d_in, const int* in_sizes, int n_in,
                              void* d_out, int out_size, void* d_ws, size_t ws_size,
                              hipStream_t stream) {
    const int*   w = (const int*)d_in[0];
    const float* z = (const float*)d_in[1];
    const float* W = (const float*)d_in[2];
    const float* b = (const float*)d_in[3];
    float* out = (float*)d_out;

    dim3 grid(L_DIM / CG, L_DIM / JT);   // (256, 4)
    pnet_fused<<<grid, 256, 0, stream>>>(w, z, W, b, out);
}